// Round 1
// baseline (466.534 us; speedup 1.0000x reference)
//
#include <hip/hip_runtime.h>
#include <hip/hip_bf16.h>
#include <math.h>

// Problem constants (from reference): B=131072, D=512, C=5, K=10
#define BATCH   131072
#define DIM     512
#define NCLS    5
#define NEXP    10
#define NW      60            // 10 gate cols + 50 expert cols
#define NWPAD   64            // padded row stride of Wpack
#define TPB     256
#define CHUNK   32            // D-chunk staged in LDS
#define LSTRIDE 33            // +1 pad: column reads -> 2-way bank alias (free)

// ---------------------------------------------------------------------------
// Pack Wg [D,K] and We [K,D,C] into Wpack[d][j] (j<10: gate col j, j=10+5k+c:
// expert k class c), so per-d weight rows are contiguous + wave-uniform.
// Also pack biases into bpack[64] with the same j layout.
// ---------------------------------------------------------------------------
__global__ void pack_w_kernel(const float* __restrict__ We,
                              const float* __restrict__ be,
                              const float* __restrict__ Wg,
                              const float* __restrict__ bg,
                              float* __restrict__ wpack,
                              float* __restrict__ bpack) {
    int idx = blockIdx.x * TPB + threadIdx.x;     // 0 .. 512*64-1
    int d = idx >> 6;
    int j = idx & 63;
    float v = 0.0f;
    if (j < NEXP) {
        v = Wg[d * NEXP + j];                     // Wg[d][j]
    } else if (j < NW) {
        int k = (j - NEXP) / NCLS;
        int c = (j - NEXP) % NCLS;
        v = We[(k * DIM + d) * NCLS + c];         // We[k][d][c]
    }
    wpack[idx] = v;
    if (idx < NWPAD) {
        float bv = 0.0f;
        if (idx < NEXP) bv = bg[idx];
        else if (idx < NW) {
            int k = (idx - NEXP) / NCLS;
            int c = (idx - NEXP) % NCLS;
            bv = be[k * NCLS + c];
        }
        bpack[idx] = bv;
    }
}

// ---------------------------------------------------------------------------
// Main kernel: one thread per batch row. emb tile staged via LDS (coalesced
// global float4 loads), 60 fp32 accumulators per thread, W rows read with
// wave-uniform addresses (scalar-load path). Epilogue: softmax(10) +
// relu + gate-weighted sum -> out[row][0..4].
// ---------------------------------------------------------------------------
__global__ __launch_bounds__(TPB) void moe_head_kernel(
        const float* __restrict__ emb,
        const float* __restrict__ wpack,
        const float* __restrict__ bpack,
        float* __restrict__ out) {
    __shared__ float tile[TPB * LSTRIDE];         // 256 x 33 floats = 33.8 KB

    const int tid = threadIdx.x;
    const int rowBase = blockIdx.x * TPB;
    const int myRow = rowBase + tid;

    float acc[NW];
    #pragma unroll
    for (int j = 0; j < NW; ++j) acc[j] = 0.0f;

    const float4* embv = reinterpret_cast<const float4*>(emb);

    for (int ch = 0; ch < DIM / CHUNK; ++ch) {
        __syncthreads();                          // protect tile from prev compute
        // ---- stage: 256 rows x 32 floats, coalesced float4 loads ----
        #pragma unroll
        for (int p = 0; p < (TPB * CHUNK / 4) / TPB; ++p) {   // 8 passes
            int linear = p * TPB + tid;
            int r = linear >> 3;                  // row within tile
            int q = linear & 7;                   // float4 index within 32-wide chunk
            float4 v = embv[(size_t)(rowBase + r) * (DIM / 4) + ch * (CHUNK / 4) + q];
            int la = r * LSTRIDE + q * 4;
            tile[la + 0] = v.x;
            tile[la + 1] = v.y;
            tile[la + 2] = v.z;
            tile[la + 3] = v.w;
        }
        __syncthreads();
        // ---- compute: per d, 1 LDS read + 60 FMAs ----
        const float* wp = wpack + ch * CHUNK * NWPAD;
        #pragma unroll 4
        for (int dd = 0; dd < CHUNK; ++dd) {
            float ev = tile[tid * LSTRIDE + dd];
            const float* wr = wp + dd * NWPAD;    // wave-uniform address
            #pragma unroll
            for (int j = 0; j < NW; ++j) {
                acc[j] = fmaf(ev, wr[j], acc[j]);
            }
        }
    }

    // ---- epilogue ----
    float g[NEXP];
    float m = -INFINITY;
    #pragma unroll
    for (int k = 0; k < NEXP; ++k) {
        g[k] = acc[k] + bpack[k];
        m = fmaxf(m, g[k]);
    }
    float s = 0.0f;
    #pragma unroll
    for (int k = 0; k < NEXP; ++k) {
        g[k] = __expf(g[k] - m);
        s += g[k];
    }
    float inv = 1.0f / s;

    float o[NCLS] = {0.0f, 0.0f, 0.0f, 0.0f, 0.0f};
    #pragma unroll
    for (int k = 0; k < NEXP; ++k) {
        float gk = g[k] * inv;
        #pragma unroll
        for (int c = 0; c < NCLS; ++c) {
            float e = acc[NEXP + k * NCLS + c] + bpack[NEXP + k * NCLS + c];
            e = fmaxf(e, 0.0f);
            o[c] = fmaf(gk, e, o[c]);
        }
    }
    size_t ob = (size_t)myRow * NCLS;
    #pragma unroll
    for (int c = 0; c < NCLS; ++c) out[ob + c] = o[c];
}

extern "C" void kernel_launch(void* const* d_in, const int* in_sizes, int n_in,
                              void* d_out, int out_size, void* d_ws, size_t ws_size,
                              hipStream_t stream) {
    const float* emb = (const float*)d_in[0];   // [B, D]
    const float* We  = (const float*)d_in[1];   // [K, D, C]
    const float* be  = (const float*)d_in[2];   // [K, C]
    const float* Wg  = (const float*)d_in[3];   // [D, K]
    const float* bg  = (const float*)d_in[4];   // [K]
    float* out = (float*)d_out;                 // [B, C]

    float* wpack = (float*)d_ws;                // 512*64 floats
    float* bpack = wpack + DIM * NWPAD;         // 64 floats

    pack_w_kernel<<<(DIM * NWPAD) / TPB, TPB, 0, stream>>>(We, be, Wg, bg, wpack, bpack);
    moe_head_kernel<<<BATCH / TPB, TPB, 0, stream>>>(emb, wpack, bpack, out);
}

// Round 2
// 370.643 us; speedup vs baseline: 1.2587x; 1.2587x over previous
//
#include <hip/hip_runtime.h>
#include <hip/hip_bf16.h>
#include <math.h>

// Problem: B=131072, D=512, C=5, K=10 experts.
// One GEMM [B,512] x [512,64pad] in bf16 MFMA + per-row softmax/relu epilogue.
#define BATCH   131072
#define DIM     512
#define NCLS    5
#define NEXP    10
#define NW      60            // 10 gate cols + 50 expert cols
#define NCOL    64            // padded col count (4 MFMA col-tiles of 16)
#define TPB     256
#define ROWS_PER_BLOCK 64     // 4 waves x 16 rows
#define EPS_STRIDE 68         // LDS epilogue row stride (floats)

typedef short bf16x8 __attribute__((ext_vector_type(8)));   // MFMA A/B frag (4 VGPRs)
typedef float f32x4  __attribute__((ext_vector_type(4)));   // MFMA C/D frag

// ---------------------------------------------------------------------------
// Pack weights into exact per-lane B-fragment order for mfma_f32_16x16x32_bf16:
//   B[k = (lane>>4)*8 + j][n = lane&15]  for k-chunk c (k = 32c + ...), col-tile t
//   (n_global = 16t + (lane&15)).
// Layout: wfrag[((c*4 + t)*64 + lane)*8 + j]  as bf16 bits (ushort).
// Column semantics: n<10 -> gate col n (Wg[d][n]); 10<=n<60 -> expert
// k=(n-10)/5, class c=(n-10)%5 (We[k][d][c]); n>=60 -> 0 pad.
// Also bpack[64] fp32 biases in the same n layout.
// ---------------------------------------------------------------------------
__global__ void pack_w_kernel(const float* __restrict__ We,
                              const float* __restrict__ be,
                              const float* __restrict__ Wg,
                              const float* __restrict__ bg,
                              unsigned short* __restrict__ wfrag,
                              float* __restrict__ bpack) {
    int idx = blockIdx.x * TPB + threadIdx.x;   // 0 .. 32767
    int c    = idx >> 11;                       // k-chunk 0..15
    int t    = (idx >> 9) & 3;                  // col tile 0..3
    int lane = (idx >> 3) & 63;
    int j    = idx & 7;
    int d = c * 32 + (lane >> 4) * 8 + j;       // 0..511
    int n = t * 16 + (lane & 15);               // 0..63
    float v = 0.0f;
    if (n < NEXP) {
        v = Wg[d * NEXP + n];
    } else if (n < NW) {
        int k  = (n - NEXP) / NCLS;
        int cc = (n - NEXP) % NCLS;
        v = We[(k * DIM + d) * NCLS + cc];
    }
    wfrag[idx] = __builtin_bit_cast(unsigned short, __float2bfloat16(v));
    if (idx < NCOL) {
        float bv = 0.0f;
        if (idx < NEXP) bv = bg[idx];
        else if (idx < NW) {
            int k  = (idx - NEXP) / NCLS;
            int cc = (idx - NEXP) % NCLS;
            bv = be[k * NCLS + cc];
        }
        bpack[idx] = bv;
    }
}

// ---------------------------------------------------------------------------
// Main kernel: 4 waves/block, each wave computes a 16-row x 64-col tile.
// K-loop is barrier-free: A streamed from global (fp32 -> bf16 cvt),
// B fragments from the packed L2-resident wfrag. Epilogue via one LDS
// round-trip to transpose MFMA C-layout into per-thread rows.
// ---------------------------------------------------------------------------
__global__ __launch_bounds__(TPB) void moe_mfma_kernel(
        const float* __restrict__ emb,
        const unsigned short* __restrict__ wfrag_u,
        const float* __restrict__ bpack,
        float* __restrict__ out) {
    __shared__ float eps[ROWS_PER_BLOCK * EPS_STRIDE];   // 64 x 68 floats = 17.4 KB

    const int tid = threadIdx.x;
    const int w   = tid >> 6;          // wave 0..3
    const int L   = tid & 63;          // lane
    const int r   = L & 15;            // A row within tile / B col within tile
    const int q   = L >> 4;            // quad 0..3

    const size_t rowBase = (size_t)blockIdx.x * ROWS_PER_BLOCK + w * 16;
    // A: lane reads emb[rowBase + r][32c + q*8 .. +8) each chunk
    const float* arow = emb + (rowBase + r) * DIM + q * 8;
    const bf16x8* bp = reinterpret_cast<const bf16x8*>(wfrag_u);

    f32x4 acc0 = {0.f, 0.f, 0.f, 0.f};
    f32x4 acc1 = acc0, acc2 = acc0, acc3 = acc0;

    #pragma unroll 2
    for (int c = 0; c < DIM / 32; ++c) {
        const float4* a4 = reinterpret_cast<const float4*>(arow + (size_t)c * 32);
        float4 a0 = a4[0];
        float4 a1 = a4[1];
        // B fragments: coalesced dwordx4, L1/L2 resident (reused by all blocks)
        bf16x8 b0 = bp[(c * 4 + 0) * 64 + L];
        bf16x8 b1 = bp[(c * 4 + 1) * 64 + L];
        bf16x8 b2 = bp[(c * 4 + 2) * 64 + L];
        bf16x8 b3 = bp[(c * 4 + 3) * 64 + L];
        float av[8] = {a0.x, a0.y, a0.z, a0.w, a1.x, a1.y, a1.z, a1.w};
        bf16x8 af;
        #pragma unroll
        for (int j = 0; j < 8; ++j)
            af[j] = (short)__builtin_bit_cast(unsigned short, __float2bfloat16(av[j]));
        acc0 = __builtin_amdgcn_mfma_f32_16x16x32_bf16(af, b0, acc0, 0, 0, 0);
        acc1 = __builtin_amdgcn_mfma_f32_16x16x32_bf16(af, b1, acc1, 0, 0, 0);
        acc2 = __builtin_amdgcn_mfma_f32_16x16x32_bf16(af, b2, acc2, 0, 0, 0);
        acc3 = __builtin_amdgcn_mfma_f32_16x16x32_bf16(af, b3, acc3, 0, 0, 0);
    }

    // Scatter C fragments to LDS: C/D layout col=lane&15, row=quad*4+reg
    // bank = (16q + r + const) % 32 -> 2-way alias only (free).
    #pragma unroll
    for (int i = 0; i < 4; ++i) {
        int rowl = w * 16 + q * 4 + i;
        eps[rowl * EPS_STRIDE +  0 + r] = acc0[i];
        eps[rowl * EPS_STRIDE + 16 + r] = acc1[i];
        eps[rowl * EPS_STRIDE + 32 + r] = acc2[i];
        eps[rowl * EPS_STRIDE + 48 + r] = acc3[i];
    }
    __syncthreads();

    // Epilogue: one thread per row (first wave only; tiny)
    if (tid < ROWS_PER_BLOCK) {
        const float* row = eps + tid * EPS_STRIDE;
        float g[NEXP];
        float m = -INFINITY;
        #pragma unroll
        for (int k = 0; k < NEXP; ++k) {
            g[k] = row[k] + bpack[k];
            m = fmaxf(m, g[k]);
        }
        float s = 0.0f;
        #pragma unroll
        for (int k = 0; k < NEXP; ++k) {
            g[k] = __expf(g[k] - m);
            s += g[k];
        }
        float inv = 1.0f / s;

        float o[NCLS] = {0.f, 0.f, 0.f, 0.f, 0.f};
        #pragma unroll
        for (int k = 0; k < NEXP; ++k) {
            float gk = g[k] * inv;
            #pragma unroll
            for (int cc = 0; cc < NCLS; ++cc) {
                int n = NEXP + k * NCLS + cc;
                float e = row[n] + bpack[n];
                e = fmaxf(e, 0.0f);
                o[cc] = fmaf(gk, e, o[cc]);
            }
        }
        size_t ob = ((size_t)blockIdx.x * ROWS_PER_BLOCK + tid) * NCLS;
        #pragma unroll
        for (int cc = 0; cc < NCLS; ++cc) out[ob + cc] = o[cc];
    }
}

extern "C" void kernel_launch(void* const* d_in, const int* in_sizes, int n_in,
                              void* d_out, int out_size, void* d_ws, size_t ws_size,
                              hipStream_t stream) {
    const float* emb = (const float*)d_in[0];   // [B, D]
    const float* We  = (const float*)d_in[1];   // [K, D, C]
    const float* be  = (const float*)d_in[2];   // [K, C]
    const float* Wg  = (const float*)d_in[3];   // [D, K]
    const float* bg  = (const float*)d_in[4];   // [K]
    float* out = (float*)d_out;                 // [B, C]

    unsigned short* wfrag = (unsigned short*)d_ws;            // 16*4*64*8 = 32768 ushort
    float* bpack = (float*)((char*)d_ws + 32768 * sizeof(unsigned short));

    pack_w_kernel<<<(16 * 4 * 64 * 8) / TPB, TPB, 0, stream>>>(We, be, Wg, bg, wfrag, bpack);
    moe_mfma_kernel<<<BATCH / ROWS_PER_BLOCK, TPB, 0, stream>>>(emb, wfrag, bpack, out);
}

// Round 3
// 361.994 us; speedup vs baseline: 1.2888x; 1.0239x over previous
//
#include <hip/hip_runtime.h>
#include <hip/hip_bf16.h>
#include <math.h>

// Problem: B=131072, D=512, C=5, K=10 experts.
// One GEMM [B,512] x [512,64pad] in bf16 MFMA + per-row softmax/relu epilogue.
// B matrix (64 KB packed bf16 fragments) staged in LDS once per block.
#define BATCH   131072
#define DIM     512
#define NCLS    5
#define NEXP    10
#define NW      60            // 10 gate cols + 50 expert cols
#define NCOL    64            // padded col count (4 MFMA col-tiles of 16)
#define PACK_TPB 256
#define TPB     512           // 8 waves/block
#define ROWS_PER_BLOCK 128    // 8 waves x 16 rows
#define EPS_STRIDE 68         // epilogue LDS row stride (floats); 2-way alias only

typedef short bf16x8 __attribute__((ext_vector_type(8)));   // MFMA A/B frag (4 VGPRs)
typedef float f32x4  __attribute__((ext_vector_type(4)));   // MFMA C/D frag

// ---------------------------------------------------------------------------
// Pack weights into per-lane B-fragment order for mfma_f32_16x16x32_bf16:
// wfrag[((c*4 + t)*64 + lane)*8 + j] = B[k = 32c + (lane>>4)*8 + j][n = 16t + (lane&15)]
// n<10: gate col (Wg); 10<=n<60: expert (n-10)/5 class (n-10)%5 (We); else 0.
// bpack[64]: fp32 biases in the same n layout.
// ---------------------------------------------------------------------------
__global__ void pack_w_kernel(const float* __restrict__ We,
                              const float* __restrict__ be,
                              const float* __restrict__ Wg,
                              const float* __restrict__ bg,
                              unsigned short* __restrict__ wfrag,
                              float* __restrict__ bpack) {
    int idx = blockIdx.x * PACK_TPB + threadIdx.x;   // 0 .. 32767
    int c    = idx >> 11;                       // k-chunk 0..15
    int t    = (idx >> 9) & 3;                  // col tile 0..3
    int lane = (idx >> 3) & 63;
    int j    = idx & 7;
    int d = c * 32 + (lane >> 4) * 8 + j;       // 0..511
    int n = t * 16 + (lane & 15);               // 0..63
    float v = 0.0f;
    if (n < NEXP) {
        v = Wg[d * NEXP + n];
    } else if (n < NW) {
        int k  = (n - NEXP) / NCLS;
        int cc = (n - NEXP) % NCLS;
        v = We[(k * DIM + d) * NCLS + cc];
    }
    wfrag[idx] = __builtin_bit_cast(unsigned short, __float2bfloat16(v));
    if (idx < NCOL) {
        float bv = 0.0f;
        if (idx < NEXP) bv = bg[idx];
        else if (idx < NW) {
            int k  = (idx - NEXP) / NCLS;
            int cc = (idx - NEXP) % NCLS;
            bv = be[k * NCLS + cc];
        }
        bpack[idx] = bv;
    }
}

// ---------------------------------------------------------------------------
// Main kernel: 8 waves/block, each wave computes a 16-row x 64-col tile.
// B fragments staged to LDS once (64 KB), K-loop reads B via conflict-free
// ds_read_b128; A streamed from global (fp32 -> bf16 cvt), no K-loop barrier.
// Epilogue reuses the B LDS region (B dead after K-loop).
// ---------------------------------------------------------------------------
__global__ __launch_bounds__(TPB) void moe_mfma_kernel(
        const float* __restrict__ emb,
        const float4* __restrict__ wfrag4,
        const float* __restrict__ bpack,
        float* __restrict__ out) {
    __shared__ float4 smem4[4096];   // 64 KB: B fragments; reused as epilogue buf

    const int tid = threadIdx.x;

    // ---- stage B: 64 KB, coalesced float4, once per block ----
    #pragma unroll
    for (int i = 0; i < 8; ++i)
        smem4[i * TPB + tid] = wfrag4[i * TPB + tid];
    __syncthreads();

    const int w = tid >> 6;            // wave 0..7
    const int L = tid & 63;            // lane
    const int r = L & 15;              // A row within tile
    const int q = L >> 4;              // quad 0..3

    const size_t rowBase = (size_t)blockIdx.x * ROWS_PER_BLOCK + w * 16;
    const float* arow = emb + (rowBase + r) * DIM + q * 8;
    const bf16x8* bl = reinterpret_cast<const bf16x8*>(smem4);

    f32x4 acc0 = {0.f, 0.f, 0.f, 0.f};
    f32x4 acc1 = acc0, acc2 = acc0, acc3 = acc0;

    #pragma unroll 4
    for (int c = 0; c < DIM / 32; ++c) {
        const float4* a4 = reinterpret_cast<const float4*>(arow + (size_t)c * 32);
        float4 a0 = a4[0];
        float4 a1 = a4[1];
        // B from LDS: lane-linear, 64 lanes x 16 B contiguous -> conflict-free
        bf16x8 b0 = bl[(c * 4 + 0) * 64 + L];
        bf16x8 b1 = bl[(c * 4 + 1) * 64 + L];
        bf16x8 b2 = bl[(c * 4 + 2) * 64 + L];
        bf16x8 b3 = bl[(c * 4 + 3) * 64 + L];
        float av[8] = {a0.x, a0.y, a0.z, a0.w, a1.x, a1.y, a1.z, a1.w};
        bf16x8 af;
        #pragma unroll
        for (int j = 0; j < 8; ++j)
            af[j] = (short)__builtin_bit_cast(unsigned short, __float2bfloat16(av[j]));
        acc0 = __builtin_amdgcn_mfma_f32_16x16x32_bf16(af, b0, acc0, 0, 0, 0);
        acc1 = __builtin_amdgcn_mfma_f32_16x16x32_bf16(af, b1, acc1, 0, 0, 0);
        acc2 = __builtin_amdgcn_mfma_f32_16x16x32_bf16(af, b2, acc2, 0, 0, 0);
        acc3 = __builtin_amdgcn_mfma_f32_16x16x32_bf16(af, b3, acc3, 0, 0, 0);
    }

    // ---- epilogue: reuse B's LDS for the C transpose ----
    __syncthreads();                   // all waves done reading B
    float* eps = reinterpret_cast<float*>(smem4);   // 128 x 68 floats = 34.8 KB
    // C/D layout: col = lane&15, row = quad*4 + reg.
    // bank = (16q + 4i + r) % 32 for fixed i -> 2-way alias only (free).
    #pragma unroll
    for (int i = 0; i < 4; ++i) {
        int rowl = w * 16 + q * 4 + i;
        eps[rowl * EPS_STRIDE +  0 + r] = acc0[i];
        eps[rowl * EPS_STRIDE + 16 + r] = acc1[i];
        eps[rowl * EPS_STRIDE + 32 + r] = acc2[i];
        eps[rowl * EPS_STRIDE + 48 + r] = acc3[i];
    }
    __syncthreads();

    // One thread per row: softmax(10) + relu + gate-weighted sum -> 5 outputs
    if (tid < ROWS_PER_BLOCK) {
        const float* row = eps + tid * EPS_STRIDE;
        float g[NEXP];
        float m = -INFINITY;
        #pragma unroll
        for (int k = 0; k < NEXP; ++k) {
            g[k] = row[k] + bpack[k];
            m = fmaxf(m, g[k]);
        }
        float s = 0.0f;
        #pragma unroll
        for (int k = 0; k < NEXP; ++k) {
            g[k] = __expf(g[k] - m);
            s += g[k];
        }
        float inv = 1.0f / s;

        float o[NCLS] = {0.f, 0.f, 0.f, 0.f, 0.f};
        #pragma unroll
        for (int k = 0; k < NEXP; ++k) {
            float gk = g[k] * inv;
            #pragma unroll
            for (int cc = 0; cc < NCLS; ++cc) {
                int n = NEXP + k * NCLS + cc;
                float e = row[n] + bpack[n];
                e = fmaxf(e, 0.0f);
                o[cc] = fmaf(gk, e, o[cc]);
            }
        }
        size_t ob = ((size_t)blockIdx.x * ROWS_PER_BLOCK + tid) * NCLS;
        #pragma unroll
        for (int cc = 0; cc < NCLS; ++cc) out[ob + cc] = o[cc];
    }
}

extern "C" void kernel_launch(void* const* d_in, const int* in_sizes, int n_in,
                              void* d_out, int out_size, void* d_ws, size_t ws_size,
                              hipStream_t stream) {
    const float* emb = (const float*)d_in[0];   // [B, D]
    const float* We  = (const float*)d_in[1];   // [K, D, C]
    const float* be  = (const float*)d_in[2];   // [K, C]
    const float* Wg  = (const float*)d_in[3];   // [D, K]
    const float* bg  = (const float*)d_in[4];   // [K]
    float* out = (float*)d_out;                 // [B, C]

    unsigned short* wfrag = (unsigned short*)d_ws;            // 32768 ushort = 64 KB
    float* bpack = (float*)((char*)d_ws + 32768 * sizeof(unsigned short));

    pack_w_kernel<<<(16 * 4 * 64 * 8) / PACK_TPB, PACK_TPB, 0, stream>>>(
        We, be, Wg, bg, wfrag, bpack);
    moe_mfma_kernel<<<BATCH / ROWS_PER_BLOCK, TPB, 0, stream>>>(
        emb, (const float4*)wfrag, bpack, out);
}